// Round 4
// baseline (369.487 us; speedup 1.0000x reference)
//
#include <hip/hip_runtime.h>

// Encoder: 2-layer LSTM (H=16 each), x [B=16384, T=100, I=18], FP32 in/out.
// One wave per 16-batch tile; gates via mfma_f32_16x16x32_bf16, gate blocks
// i,f,g,o = the four N-tiles so i/f/g/o of a (batch,unit) land in one lane.
// PRECISION: every MFMA operand is carried as a two-term bf16 split
// (hi + lo ~= 17 mantissa bits): x, all weights, h1, relu(h1), h2. Only
// lo*lo cross terms are dropped (~2^-18 rel). Gate math / biases / c in fp32.
// R4 FIX: the x-prefetch clamp corrupted the t=99 load of the last batch tile
// (valid address > clamp address). Replaced with a wave-uniform time guard:
// at t==99 prefetch from the always-valid t=0 address (result discarded).
// h state round-trips C-layout -> A-layout via wave-private LDS (row stride
// 52 dwords: write banks 2-way max = free; 16B-aligned b128 reads; no
// barriers -- DS is in-order within a wave).

typedef float f32x4 __attribute__((ext_vector_type(4)));
typedef __bf16 bf16x8 __attribute__((ext_vector_type(8)));
typedef unsigned int uint32x4 __attribute__((ext_vector_type(4)));

union FragU {
  bf16x8 v;
  unsigned short u[8];
  unsigned int d[4];
  uint32x4 q;
};

#define MFMA16(A, B, C) __builtin_amdgcn_mfma_f32_16x16x32_bf16((A), (B), (C), 0, 0, 0)

static __device__ __forceinline__ unsigned short f2bf(float f) {  // RNE
  unsigned int u = __builtin_bit_cast(unsigned int, f);
  u = u + 0x7FFFu + ((u >> 16) & 1u);
  return (unsigned short)(u >> 16);
}
static __device__ __forceinline__ float bfbits2f(unsigned short h) {
  unsigned int u = ((unsigned int)h) << 16;
  return __builtin_bit_cast(float, u);
}
static __device__ __forceinline__ float sigm(float x) {
  // 1/(1+exp(-x)); saturates cleanly (exp2->inf => rcp->0), never NaN.
  return __builtin_amdgcn_rcpf(1.0f + __builtin_amdgcn_exp2f(x * -1.4426950408889634f));
}
static __device__ __forceinline__ float tanh_(float x) {
  // 1 - 2/(1+exp(2x)); saturates to +-1 for large |x|.
  return 1.0f - 2.0f * __builtin_amdgcn_rcpf(1.0f + __builtin_amdgcn_exp2f(x * 2.8853900817779268f));
}

// LDS geometry (per wave, dword units): 16 rows x 52 dwords; rows 16B-aligned
// (52*4 = 208 = 13*16). Row m = batch; dword n of region R = (hi | lo<<16)
// for unit n. Regions: H1 +0, RELU +16, H2 +32, pad 48..51.
// Write bank = (16*(g&1) + 20r + R + n) mod 32 -> exactly 2 lanes/bank (free).
#define ROWD 52
#define WAVED (16 * ROWD)  // 832 dwords per wave

__global__ __launch_bounds__(256, 1) void enc_kernel(
    const float* __restrict__ x,     // [16384,100,18]
    const float* __restrict__ Wih1,  // [64,18]
    const float* __restrict__ Whh1,  // [64,16]
    const float* __restrict__ bih1,  // [64]
    const float* __restrict__ bhh1,  // [64]
    const float* __restrict__ Wih2,  // [64,16]
    const float* __restrict__ Whh2,  // [64,16]
    const float* __restrict__ bih2,  // [64]
    const float* __restrict__ bhh2,  // [64]
    float* __restrict__ out)         // [16384,16]
{
  __shared__ __align__(16) unsigned int lds[4 * WAVED];

  const int tid  = threadIdx.x;
  const int wv   = tid >> 6;
  const int lane = tid & 63;
  const int n    = lane & 15;  // A row (batch) / B col (unit) / C col (unit)
  const int g    = lane >> 4;  // A/B k-group; C row-quad

  unsigned int* const my = &lds[wv * WAVED];
  uint32x4* const myq = (uint32x4*)my;

  // Zero wave-private scratch (H1/RELU/H2 read as 0 at t=0). 832 = 13*64.
#pragma unroll
  for (int i = 0; i < 13; ++i) my[lane + 64 * i] = 0u;

  const int b0 = (blockIdx.x * 4 + wv) * 16;

  // ---- loop-invariant weight fragments (B layout: col=lane&15, k=8g+j) ----
  // hi = bf16(W), lo = bf16(W - hi). Recurrent weights duplicated along K
  // (kk = k>>1) to pair with hi/lo-interleaved A fragments.
  FragU B1h[4], B1l[4], B2h[4], B2l[4], B3h[4], B3l[4], B4h[4], B4l[4];
  float bias1s[4], bias2s[4];
#pragma unroll
  for (int tn = 0; tn < 4; ++tn) {  // 0=i 1=f 2=g 3=o (PyTorch gate order)
    const int row = tn * 16 + n;
#pragma unroll
    for (int j = 0; j < 8; ++j) {
      const int k = 8 * g + j;
      if (k < 18) {
        const float w = Wih1[row * 18 + k];
        B1h[tn].u[j] = f2bf(w);
        B1l[tn].u[j] = f2bf(w - bfbits2f(B1h[tn].u[j]));
      } else {
        B1h[tn].u[j] = 0;
        B1l[tn].u[j] = 0;
      }
      const int kk = k >> 1;  // hi/lo interleave: both K slots share the weight
      const float w2 = Whh1[row * 16 + kk];
      const float w3 = Wih2[row * 16 + kk];
      const float w4 = Whh2[row * 16 + kk];
      B2h[tn].u[j] = f2bf(w2); B2l[tn].u[j] = f2bf(w2 - bfbits2f(B2h[tn].u[j]));
      B3h[tn].u[j] = f2bf(w3); B3l[tn].u[j] = f2bf(w3 - bfbits2f(B3h[tn].u[j]));
      B4h[tn].u[j] = f2bf(w4); B4l[tn].u[j] = f2bf(w4 - bfbits2f(B4h[tn].u[j]));
    }
    bias1s[tn] = bih1[row] + bhh1[row];
    bias2s[tn] = bih2[row] + bhh2[row];
  }

  // ---- loop-invariant LDS indices ----
  const int rdH1 = 13 * n + 0 + g;  // uint4 idx: h1 hi/lo (A-frag, layer-1 rec)
  const int rdF1 = 13 * n + 4 + g;  // relu(h1)
  const int rdF2 = 13 * n + 8 + g;  // h2
  int wrH[4], wrR[4], wrH2[4];      // dword indices, row m = 4g+r
#pragma unroll
  for (int r = 0; r < 4; ++r) {
    const int m = 4 * g + r;
    wrH[r]  = m * ROWD + 0  + n;
    wrR[r]  = m * ROWD + 16 + n;
    wrH2[r] = m * ROWD + 32 + n;
  }

  // ---- x addressing: lane reads x[b0+n][t][8g .. 8g+7] (fp32) ----
  const float* const x0 = x + (size_t)(b0 + n) * 1800 + 8 * g;  // t=0, always valid
  const float* xp = x0;

  auto loadx = [&](const float* p, FragU& hi, FragU& lo) {
    hi.q = (uint32x4){0u, 0u, 0u, 0u};
    lo.q = (uint32x4){0u, 0u, 0u, 0u};
    if (g < 2) {  // k 0..15
#pragma unroll
      for (int j = 0; j < 8; j += 2) {
        float2 a = *(const float2*)(p + j);
        hi.u[j]     = f2bf(a.x);
        lo.u[j]     = f2bf(a.x - bfbits2f(hi.u[j]));
        hi.u[j + 1] = f2bf(a.y);
        lo.u[j + 1] = f2bf(a.y - bfbits2f(hi.u[j + 1]));
      }
    } else if (g == 2) {  // k 16,17 (B1 zero-pad covers k>=18)
      float2 a = *(const float2*)(p);
      hi.u[0] = f2bf(a.x);
      lo.u[0] = f2bf(a.x - bfbits2f(hi.u[0]));
      hi.u[1] = f2bf(a.y);
      lo.u[1] = f2bf(a.y - bfbits2f(hi.u[1]));
    }
  };

  FragU xh, xl;
  loadx(xp, xh, xl);
  FragU ha;  ha.q = (uint32x4){0u, 0u, 0u, 0u};  // h1_{-1} = 0 (hi|lo packed)
  float c1[4] = {0.f, 0.f, 0.f, 0.f};
  float c2[4] = {0.f, 0.f, 0.f, 0.f};
  float h2v[4] = {0.f, 0.f, 0.f, 0.f};

#pragma unroll 2
  for (int t = 0; t < 100; ++t) {
    // Early read: h2_{t-1} (written end of previous iter; same-wave DS order).
    FragU f2;  f2.q = myq[rdF2];

    // ---- Layer-1 gates: (x_hi+x_lo)@W1_hi + x_hi@W1_lo + (h)@(W2_hi+W2_lo) + b1
    f32x4 ga[4];
#pragma unroll
    for (int tn = 0; tn < 4; ++tn) {
      f32x4 acc = (f32x4){bias1s[tn], bias1s[tn], bias1s[tn], bias1s[tn]};
      acc = MFMA16(xh.v, B1h[tn].v, acc);
      acc = MFMA16(xl.v, B1h[tn].v, acc);
      acc = MFMA16(xh.v, B1l[tn].v, acc);
      acc = MFMA16(ha.v, B2h[tn].v, acc);
      acc = MFMA16(ha.v, B2l[tn].v, acc);
      ga[tn] = acc;
    }

    // Prefetch x_{t+1}. Wave-uniform guard: at t==99 the prefetch is discarded,
    // so read the (always-valid) t=0 address instead of clamping into garbage.
    xp += 18;
    FragU xhn, xln;
    loadx(t < 99 ? xp : x0, xhn, xln);

    // ---- Layer-1 elementwise: lane owns i,f,g,o of 4 (batch,unit) pairs ----
    unsigned int packH[4], packR[4];
#pragma unroll
    for (int r = 0; r < 4; ++r) {
      const float iv = sigm(ga[0][r]);
      const float fv = sigm(ga[1][r]);
      const float gv = tanh_(ga[2][r]);
      const float ov = sigm(ga[3][r]);
      const float cc = fv * c1[r] + iv * gv;
      c1[r] = cc;
      const float h = ov * tanh_(cc);
      const unsigned short hh = f2bf(h);
      const unsigned short hl = f2bf(h - bfbits2f(hh));  // exact two-term split
      packH[r] = (unsigned int)hh | ((unsigned int)hl << 16);
      const float rl = fmaxf(h, 0.f);
      const unsigned short rh = f2bf(rl);
      const unsigned short rr = f2bf(rl - bfbits2f(rh));
      packR[r] = (unsigned int)rh | ((unsigned int)rr << 16);
    }
    // relu writes first (consumed immediately); h1 writes feed next iter only.
#pragma unroll
    for (int r = 0; r < 4; ++r) my[wrR[r]] = packR[r];
    FragU f1;  f1.q = myq[rdF1];
#pragma unroll
    for (int r = 0; r < 4; ++r) my[wrH[r]] = packH[r];
    FragU hanext;  hanext.q = myq[rdH1];

    // ---- Layer-2 gates: (f1)@(W3_hi+W3_lo) + (f2)@(W4_hi+W4_lo) + b2 ----
    f32x4 gb[4];
#pragma unroll
    for (int tn = 0; tn < 4; ++tn) {
      f32x4 acc = (f32x4){bias2s[tn], bias2s[tn], bias2s[tn], bias2s[tn]};
      acc = MFMA16(f2.v, B4h[tn].v, acc);  // f2 path first (read was early)
      acc = MFMA16(f2.v, B4l[tn].v, acc);
      acc = MFMA16(f1.v, B3h[tn].v, acc);
      acc = MFMA16(f1.v, B3l[tn].v, acc);
      gb[tn] = acc;
    }

    // ---- Layer-2 elementwise ----
    unsigned int pack2[4];
#pragma unroll
    for (int r = 0; r < 4; ++r) {
      const float iv = sigm(gb[0][r]);
      const float fv = sigm(gb[1][r]);
      const float gv = tanh_(gb[2][r]);
      const float ov = sigm(gb[3][r]);
      const float cc = fv * c2[r] + iv * gv;
      c2[r] = cc;
      const float h = ov * tanh_(cc);
      h2v[r] = h;
      const unsigned short hh = f2bf(h);
      const unsigned short hl = f2bf(h - bfbits2f(hh));
      pack2[r] = (unsigned int)hh | ((unsigned int)hl << 16);
    }
#pragma unroll
    for (int r = 0; r < 4; ++r) my[wrH2[r]] = pack2[r];

    xh = xhn;
    xl = xln;
    ha = hanext;
  }

  // ---- output: relu(h2_last) fp32; lane holds batches 4g+r, unit n ----
#pragma unroll
  for (int r = 0; r < 4; ++r) {
    out[(size_t)(b0 + 4 * g + r) * 16 + n] = fmaxf(h2v[r], 0.f);
  }
}

extern "C" void kernel_launch(void* const* d_in, const int* in_sizes, int n_in,
                              void* d_out, int out_size, void* d_ws, size_t ws_size,
                              hipStream_t stream) {
  (void)in_sizes; (void)n_in; (void)d_ws; (void)ws_size; (void)out_size;
  // 16384 batch / 16 per wave / 4 waves per block = 256 blocks (1 per CU).
  enc_kernel<<<dim3(256), dim3(256), 0, stream>>>(
      (const float*)d_in[0],
      (const float*)d_in[1],
      (const float*)d_in[2],
      (const float*)d_in[3],
      (const float*)d_in[4],
      (const float*)d_in[5],
      (const float*)d_in[6],
      (const float*)d_in[7],
      (const float*)d_in[8],
      (float*)d_out);
}

// Round 5
// 345.909 us; speedup vs baseline: 1.0682x; 1.0682x over previous
//
#include <hip/hip_runtime.h>

// Encoder: 2-layer LSTM (H=16 each), x [B=16384, T=100, I=18], FP32 in/out.
// R5: LDS-free formulation. Compute G^T = W @ H^T (operands swapped): C/D
// layout col=lane&15=batch, row=quad*4+reg=unit. Lane (b,g) produces h for
// batch b, units 4g..4g+3, packed (hi|lo<<16) -- which IS the B-fragment
// (B[k=2*unit+part][n=batch]) for the next step's recurrent MFMA. The hi/lo
// precision interleave (K=32 = 16 units x 2) exactly matches the C-row quad
// structure => recurrence state never leaves registers. No LDS, no barriers,
// no cross-lane ops.
// PRECISION (unchanged from R4, which measured 9.77e-4 vs 3.9e-3 threshold):
// two-term bf16 splits on x and all weights; gate math / biases / c in fp32;
// only lo*lo cross terms dropped.
// Weight fragments are content-identical to R4 (lane&15 = m for A operand).

typedef float f32x4 __attribute__((ext_vector_type(4)));
typedef __bf16 bf16x8 __attribute__((ext_vector_type(8)));
typedef unsigned int uint32x4 __attribute__((ext_vector_type(4)));

union FragU {
  bf16x8 v;
  unsigned short u[8];
  unsigned int d[4];
  uint32x4 q;
};

#define MFMA16(A, B, C) __builtin_amdgcn_mfma_f32_16x16x32_bf16((A), (B), (C), 0, 0, 0)

static __device__ __forceinline__ unsigned short f2bf(float f) {  // RNE (proven R4)
  unsigned int u = __builtin_bit_cast(unsigned int, f);
  u = u + 0x7FFFu + ((u >> 16) & 1u);
  return (unsigned short)(u >> 16);
}
static __device__ __forceinline__ float bfbits2f(unsigned short h) {
  unsigned int u = ((unsigned int)h) << 16;
  return __builtin_bit_cast(float, u);
}
static __device__ __forceinline__ float sigm(float x) {
  // 1/(1+exp(-x)); saturates cleanly (exp2->inf => rcp->0), never NaN.
  return __builtin_amdgcn_rcpf(1.0f + __builtin_amdgcn_exp2f(x * -1.4426950408889634f));
}
static __device__ __forceinline__ float tanh_(float x) {
  // 1 - 2/(1+exp(2x)); saturates to +-1 for large |x|.
  return 1.0f - 2.0f * __builtin_amdgcn_rcpf(1.0f + __builtin_amdgcn_exp2f(x * 2.8853900817779268f));
}

__global__ __launch_bounds__(256, 1) void enc_kernel(
    const float* __restrict__ x,     // [16384,100,18]
    const float* __restrict__ Wih1,  // [64,18]
    const float* __restrict__ Whh1,  // [64,16]
    const float* __restrict__ bih1,  // [64]
    const float* __restrict__ bhh1,  // [64]
    const float* __restrict__ Wih2,  // [64,16]
    const float* __restrict__ Whh2,  // [64,16]
    const float* __restrict__ bih2,  // [64]
    const float* __restrict__ bhh2,  // [64]
    float* __restrict__ out)         // [16384,16]
{
  const int lane = threadIdx.x & 63;
  const int b    = lane & 15;  // batch within tile: A operand m, B operand n, C col
  const int g    = lane >> 4;  // k-group for A/B; C row-quad (units 4g..4g+3)

  const int wid = (int)((blockIdx.x * blockDim.x + threadIdx.x) >> 6);
  const int b0  = wid * 16;

  // ---- loop-invariant weight A-fragments: A[m=lane&15][k=8g+j] ----
  // row = gate*16 + b; hi = bf16(W), lo = bf16(W - hi). Recurrent weights
  // duplicated along K (unit = k>>1) to pair with (hi|lo)-interleaved B frags.
  FragU A1h[4], A1l[4], A2h[4], A2l[4], A3h[4], A3l[4], A4h[4], A4l[4];
  f32x4 bias1v[4], bias2v[4];  // per-lane: gate tn, units 4g+r
#pragma unroll
  for (int tn = 0; tn < 4; ++tn) {  // 0=i 1=f 2=g 3=o (PyTorch gate order)
    const int row = tn * 16 + b;
#pragma unroll
    for (int j = 0; j < 8; ++j) {
      const int k = 8 * g + j;
      if (k < 18) {
        const float w = Wih1[row * 18 + k];
        A1h[tn].u[j] = f2bf(w);
        A1l[tn].u[j] = f2bf(w - bfbits2f(A1h[tn].u[j]));
      } else {
        A1h[tn].u[j] = 0;
        A1l[tn].u[j] = 0;
      }
      const int kk = k >> 1;  // hi/lo interleave: both K slots share the weight
      const float w2 = Whh1[row * 16 + kk];
      const float w3 = Wih2[row * 16 + kk];
      const float w4 = Whh2[row * 16 + kk];
      A2h[tn].u[j] = f2bf(w2); A2l[tn].u[j] = f2bf(w2 - bfbits2f(A2h[tn].u[j]));
      A3h[tn].u[j] = f2bf(w3); A3l[tn].u[j] = f2bf(w3 - bfbits2f(A3h[tn].u[j]));
      A4h[tn].u[j] = f2bf(w4); A4l[tn].u[j] = f2bf(w4 - bfbits2f(A4h[tn].u[j]));
    }
#pragma unroll
    for (int r = 0; r < 4; ++r) {
      const int u4 = tn * 16 + 4 * g + r;  // C row = unit 4g+r of gate tn
      bias1v[tn][r] = bih1[u4] + bhh1[u4];
      bias2v[tn][r] = bih2[u4] + bhh2[u4];
    }
  }

  // ---- x addressing: lane (b,g) reads x[b0+b][t][8g .. 8g+7] (fp32) ----
  const float* const x0 = x + (size_t)(b0 + b) * 1800 + 8 * g;  // t=0, valid
  const float* xp = x0;

  auto loadx = [&](const float* p, FragU& hi, FragU& lo) {
    hi.q = (uint32x4){0u, 0u, 0u, 0u};
    lo.q = (uint32x4){0u, 0u, 0u, 0u};
    if (g < 2) {  // k 0..15
#pragma unroll
      for (int j = 0; j < 8; j += 2) {
        float2 a = *(const float2*)(p + j);
        hi.u[j]     = f2bf(a.x);
        lo.u[j]     = f2bf(a.x - bfbits2f(hi.u[j]));
        hi.u[j + 1] = f2bf(a.y);
        lo.u[j + 1] = f2bf(a.y - bfbits2f(hi.u[j + 1]));
      }
    } else if (g == 2) {  // k 16,17 (A1 zero-pad covers k>=18)
      float2 a = *(const float2*)(p);
      hi.u[0] = f2bf(a.x);
      lo.u[0] = f2bf(a.x - bfbits2f(hi.u[0]));
      hi.u[1] = f2bf(a.y);
      lo.u[1] = f2bf(a.y - bfbits2f(hi.u[1]));
    }
  };

  FragU xh, xl;
  loadx(xp, xh, xl);

  FragU hb, rb, h2b;  // B-frags: h1 (hi|lo), relu(h1), h2 -- live in registers
  hb.q  = (uint32x4){0u, 0u, 0u, 0u};
  h2b.q = (uint32x4){0u, 0u, 0u, 0u};
  float c1[4] = {0.f, 0.f, 0.f, 0.f};
  float c2[4] = {0.f, 0.f, 0.f, 0.f};
  float h2v[4] = {0.f, 0.f, 0.f, 0.f};

#pragma unroll 2
  for (int t = 0; t < 100; ++t) {
    // ---- Layer-1 gates: G1^T = W1*(x^T) + W2*(h1^T) + b1 ----
    // x-terms first (depend only on prefetched x); recurrent terms last so the
    // critical path h1_t -> h1_{t+1} is just 2 MFMAs + elementwise.
    f32x4 ga[4];
#pragma unroll
    for (int tn = 0; tn < 4; ++tn) {
      f32x4 acc = MFMA16(A1h[tn].v, xh.v, bias1v[tn]);  // C = persistent bias regs
      acc = MFMA16(A1l[tn].v, xh.v, acc);
      acc = MFMA16(A1h[tn].v, xl.v, acc);
      acc = MFMA16(A2h[tn].v, hb.v, acc);
      acc = MFMA16(A2l[tn].v, hb.v, acc);
      ga[tn] = acc;
    }

    // Prefetch x_{t+1}. Wave-uniform guard: at t==99 result is discarded, so
    // read the always-valid t=0 address (no OOB, no clamp corruption).
    xp += 18;
    FragU xhn, xln;
    loadx(t < 99 ? xp : x0, xhn, xln);

    // ---- Layer-1 elementwise: lane (b,g) owns units 4g+r of batch b ----
    FragU hbn, rbn;
#pragma unroll
    for (int r = 0; r < 4; ++r) {
      const float iv = sigm(ga[0][r]);
      const float fv = sigm(ga[1][r]);
      const float gv = tanh_(ga[2][r]);
      const float ov = sigm(ga[3][r]);
      const float cc = fv * c1[r] + iv * gv;
      c1[r] = cc;
      const float h = ov * tanh_(cc);
      const unsigned short hh = f2bf(h);
      const unsigned short hl = f2bf(h - bfbits2f(hh));  // exact two-term split
      const unsigned int pk = (unsigned int)hh | ((unsigned int)hl << 16);
      hbn.d[r] = pk;
      rbn.d[r] = (h > 0.f) ? pk : 0u;  // relu: same split if positive, else 0
    }
    hb = hbn;
    rb = rbn;

    // ---- Layer-2 gates: G2^T = W3*(relu(h1)^T) + W4*(h2^T) + b2 ----
    f32x4 gb[4];
#pragma unroll
    for (int tn = 0; tn < 4; ++tn) {
      f32x4 acc = MFMA16(A4h[tn].v, h2b.v, bias2v[tn]);
      acc = MFMA16(A4l[tn].v, h2b.v, acc);
      acc = MFMA16(A3h[tn].v, rb.v, acc);
      acc = MFMA16(A3l[tn].v, rb.v, acc);
      gb[tn] = acc;
    }

    // ---- Layer-2 elementwise ----
    FragU h2n;
#pragma unroll
    for (int r = 0; r < 4; ++r) {
      const float iv = sigm(gb[0][r]);
      const float fv = sigm(gb[1][r]);
      const float gv = tanh_(gb[2][r]);
      const float ov = sigm(gb[3][r]);
      const float cc = fv * c2[r] + iv * gv;
      c2[r] = cc;
      const float h = ov * tanh_(cc);
      h2v[r] = h;
      const unsigned short hh = f2bf(h);
      const unsigned short hl = f2bf(h - bfbits2f(hh));
      h2n.d[r] = (unsigned int)hh | ((unsigned int)hl << 16);
    }
    h2b = h2n;

    xh = xhn;
    xl = xln;
  }

  // ---- output: relu(h2_last); lane (b,g) holds units 4g..4g+3 of batch b ----
  f32x4 o;
#pragma unroll
  for (int r = 0; r < 4; ++r) o[r] = fmaxf(h2v[r], 0.f);
  *(f32x4*)(out + (size_t)(b0 + b) * 16 + 4 * g) = o;  // 16B-aligned float4
}

extern "C" void kernel_launch(void* const* d_in, const int* in_sizes, int n_in,
                              void* d_out, int out_size, void* d_ws, size_t ws_size,
                              hipStream_t stream) {
  (void)in_sizes; (void)n_in; (void)d_ws; (void)ws_size; (void)out_size;
  // 16384 batch / 16 per wave / 4 waves per block = 256 blocks (1 per CU).
  enc_kernel<<<dim3(256), dim3(256), 0, stream>>>(
      (const float*)d_in[0],
      (const float*)d_in[1],
      (const float*)d_in[2],
      (const float*)d_in[3],
      (const float*)d_in[4],
      (const float*)d_in[5],
      (const float*)d_in[6],
      (const float*)d_in[7],
      (const float*)d_in[8],
      (float*)d_out);
}

// Round 6
// 268.264 us; speedup vs baseline: 1.3773x; 1.2894x over previous
//
#include <hip/hip_runtime.h>

// Encoder: 2-layer LSTM (H=16 each), x [B=16384, T=100, I=18], FP32 in/out.
// R6: software-pipelined, LDS-free. One wave per 16-batch tile (1024 waves =
// 1 per SIMD, structural). G^T = W @ H^T: C/D col=lane&15=batch,
// row=quad*4+reg=unit; the packed (hi|lo<<16) h dwords ARE the next step's
// B-fragment -> recurrence never leaves registers.
// Pipeline per iteration t:
//   L1-ew(t) -> L2-MFMAs(t) -> L1-MFMAs(t+1) -> x-convert(t+2) ->
//   raw-load(t+3) -> L2-ew(t)
// so MFMA latency hides under VALU work and x loads are consumed 3 steps
// after issue (no vmcnt stalls at 1 wave/SIMD).
// PRECISION: two-term splits everywhere (R4 measured 9.77e-4 vs 3.9e-3
// threshold with RNE splits). R6 uses exact trunc splits (hi=trunc16(v),
// lo=trunc16(v-hi), 5 VALU/value vs ~14): sum error <= 2^-16|v|. Weights
// keep RNE hi + lo (setup only). Gate math / biases / c-state in fp32.

typedef float f32x4 __attribute__((ext_vector_type(4)));
typedef __bf16 bf16x8 __attribute__((ext_vector_type(8)));
typedef unsigned int uint32x4 __attribute__((ext_vector_type(4)));

union FragU { bf16x8 v; unsigned short u[8]; unsigned int d[4]; uint32x4 q; };

#define MFMA16(A, B, C) __builtin_amdgcn_mfma_f32_16x16x32_bf16((A), (B), (C), 0, 0, 0)

static __device__ __forceinline__ unsigned short f2bf(float f) {  // RNE (weights)
  unsigned int u = __builtin_bit_cast(unsigned int, f);
  u = u + 0x7FFFu + ((u >> 16) & 1u);
  return (unsigned short)(u >> 16);
}
static __device__ __forceinline__ float bfbits2f(unsigned short h) {
  unsigned int u = ((unsigned int)h) << 16;
  return __builtin_bit_cast(float, u);
}
static __device__ __forceinline__ float sigm(float x) {
  // 1/(1+exp(-x)); saturates cleanly, never NaN for finite x.
  return __builtin_amdgcn_rcpf(1.0f + __builtin_amdgcn_exp2f(x * -1.4426950408889634f));
}
static __device__ __forceinline__ float tanh_(float x) {
  // 1 - 2/(1+exp(2x)); saturates to +-1.
  return 1.0f - 2.0f * __builtin_amdgcn_rcpf(1.0f + __builtin_amdgcn_exp2f(x * 2.8853900817779268f));
}
// Trunc two-term split packed as (bf_hi | bf_lo<<16). hi+lo == v to 2^-16|v|.
static __device__ __forceinline__ unsigned int split_pack(float v) {
  unsigned int u = __builtin_bit_cast(unsigned int, v);
  float hf = __builtin_bit_cast(float, u & 0xFFFF0000u);
  unsigned int l = __builtin_bit_cast(unsigned int, v - hf);
  return (u >> 16) | (l & 0xFFFF0000u);
}
// Split a float pair into hi-frag dword and lo-frag dword (9 VALU ops).
static __device__ __forceinline__ void cvt_pair(float f0, float f1,
                                                unsigned int& hd, unsigned int& ld) {
  unsigned int u0 = __builtin_bit_cast(unsigned int, f0);
  unsigned int u1 = __builtin_bit_cast(unsigned int, f1);
  unsigned int h0 = u0 & 0xFFFF0000u;
  unsigned int h1 = u1 & 0xFFFF0000u;
  hd = (u0 >> 16) | h1;
  unsigned int l0 = __builtin_bit_cast(unsigned int, f0 - __builtin_bit_cast(float, h0));
  unsigned int l1 = __builtin_bit_cast(unsigned int, f1 - __builtin_bit_cast(float, h1));
  ld = (l0 >> 16) | (l1 & 0xFFFF0000u);
}

struct RawX { float2 a, b2, c, d; };

__global__ __launch_bounds__(256, 1) void enc_kernel(
    const float* __restrict__ x,     // [16384,100,18]
    const float* __restrict__ Wih1,  // [64,18]
    const float* __restrict__ Whh1,  // [64,16]
    const float* __restrict__ bih1,  // [64]
    const float* __restrict__ bhh1,  // [64]
    const float* __restrict__ Wih2,  // [64,16]
    const float* __restrict__ Whh2,  // [64,16]
    const float* __restrict__ bih2,  // [64]
    const float* __restrict__ bhh2,  // [64]
    float* __restrict__ out)         // [16384,16]
{
  const int lane = threadIdx.x & 63;
  const int b    = lane & 15;  // batch in tile: A m-row / B n-col / C col
  const int g    = lane >> 4;  // k-group; C row-quad (units 4g..4g+3)

  const int wid = (int)((blockIdx.x * blockDim.x + threadIdx.x) >> 6);
  const int b0  = wid * 16;

  // ---- loop-invariant weight A-fragments: A[m=lane&15][k=8g+j] ----
  FragU A1h[4], A1l[4], A2h[4], A2l[4], A3h[4], A3l[4], A4h[4], A4l[4];
  f32x4 bias1v[4], bias2v[4];
#pragma unroll
  for (int tn = 0; tn < 4; ++tn) {  // 0=i 1=f 2=g 3=o (PyTorch gate order)
    const int row = tn * 16 + b;
#pragma unroll
    for (int j = 0; j < 8; ++j) {
      const int k = 8 * g + j;
      if (k < 18) {
        const float w = Wih1[row * 18 + k];
        A1h[tn].u[j] = f2bf(w);
        A1l[tn].u[j] = f2bf(w - bfbits2f(A1h[tn].u[j]));
      } else {
        A1h[tn].u[j] = 0;
        A1l[tn].u[j] = 0;
      }
      const int kk = k >> 1;  // hi/lo interleave: both K slots share the weight
      const float w2 = Whh1[row * 16 + kk];
      const float w3 = Wih2[row * 16 + kk];
      const float w4 = Whh2[row * 16 + kk];
      A2h[tn].u[j] = f2bf(w2); A2l[tn].u[j] = f2bf(w2 - bfbits2f(A2h[tn].u[j]));
      A3h[tn].u[j] = f2bf(w3); A3l[tn].u[j] = f2bf(w3 - bfbits2f(A3h[tn].u[j]));
      A4h[tn].u[j] = f2bf(w4); A4l[tn].u[j] = f2bf(w4 - bfbits2f(A4h[tn].u[j]));
    }
#pragma unroll
    for (int r = 0; r < 4; ++r) {
      const int u4 = tn * 16 + 4 * g + r;  // C row = unit 4g+r of gate tn
      bias1v[tn][r] = bih1[u4] + bhh1[u4];
      bias2v[tn][r] = bih2[u4] + bhh2[u4];
    }
  }

  // ---- x addressing: lane (b,g) covers x[b0+b][t][8g .. 8g+7] ----
  // g==3 lanes: k=24..31 are all beyond I=18; their B-slots multiply zero
  // weights (A1 pad), so they read a fixed valid address and never advance.
  const float* const x0 = x + (size_t)(b0 + b) * 1800 + 8 * g;
  const int adv = (g == 3) ? 0 : 18;

  auto loadraw = [&](const float* p) -> RawX {
    RawX r;
    r.a = *(const float2*)p;  // g<2: k 8g..8g+1; g==2: k 16,17; g==3: dummy
    if (g < 2) {              // full 8 features, in-bounds for all t
      r.b2 = *(const float2*)(p + 2);
      r.c  = *(const float2*)(p + 4);
      r.d  = *(const float2*)(p + 6);
    } else {                  // g>=2: only pair a matters (k>=18 hits A-pad)
      r.b2 = r.c = r.d = make_float2(0.f, 0.f);
    }
    return r;
  };
  auto cvt = [&](const RawX& rw, FragU& hi, FragU& lo) {
    cvt_pair(rw.a.x, rw.a.y, hi.d[0], lo.d[0]);
    cvt_pair(rw.b2.x, rw.b2.y, hi.d[1], lo.d[1]);
    cvt_pair(rw.c.x, rw.c.y, hi.d[2], lo.d[2]);
    cvt_pair(rw.d.x, rw.d.y, hi.d[3], lo.d[3]);
  };

  // ---- prologue: raw x for t=0,1,2 in flight together ----
  RawX rw0 = loadraw(x0);
  RawX rw1 = loadraw(x0 + adv);
  RawX rw  = loadraw(x0 + 2 * adv);
  const float* xq = x0 + 3 * adv;  // next load target: t=3

  FragU hb, h2b;
  hb.q  = (uint32x4){0u, 0u, 0u, 0u};  // h1_{-1}
  h2b.q = (uint32x4){0u, 0u, 0u, 0u};  // h2_{-1}
  float c1[4] = {0.f, 0.f, 0.f, 0.f};
  float c2[4] = {0.f, 0.f, 0.f, 0.f};
  float h2v[4] = {0.f, 0.f, 0.f, 0.f};

  FragU xch, xcl;
  cvt(rw0, xch, xcl);  // x(0)

  // ga = L1 gate preacts for t=0 (hb = 0)
  f32x4 ga[4];
#pragma unroll
  for (int tn = 0; tn < 4; ++tn) {
    f32x4 acc = MFMA16(A1h[tn].v, xch.v, bias1v[tn]);
    acc = MFMA16(A1l[tn].v, xch.v, acc);
    acc = MFMA16(A1h[tn].v, xcl.v, acc);
    acc = MFMA16(A2h[tn].v, hb.v, acc);
    acc = MFMA16(A2l[tn].v, hb.v, acc);
    ga[tn] = acc;
  }
  cvt(rw1, xch, xcl);  // x(1) ready for the loop's L1-MFMAs(t+1)

#pragma unroll 2
  for (int t = 0; t < 100; ++t) {
    // ---- (1) L1 elementwise (t): ga -> h1(t) as packed hi/lo ----
    FragU rb;
#pragma unroll
    for (int r = 0; r < 4; ++r) {
      const float iv = sigm(ga[0][r]);
      const float fv = sigm(ga[1][r]);
      const float gv = tanh_(ga[2][r]);
      const float ov = sigm(ga[3][r]);
      const float cc = fv * c1[r] + iv * gv;
      c1[r] = cc;
      const float h = ov * tanh_(cc);
      const unsigned int pk = split_pack(h);
      hb.d[r] = pk;
      rb.d[r] = (h > 0.f) ? pk : 0u;  // relu: identical split when positive
    }

    // ---- (2) L2 MFMAs (t): uses rb (fresh) and h2b = h2(t-1) ----
    f32x4 gb[4];
#pragma unroll
    for (int tn = 0; tn < 4; ++tn) {
      f32x4 acc = MFMA16(A4h[tn].v, h2b.v, bias2v[tn]);
      acc = MFMA16(A4l[tn].v, h2b.v, acc);
      acc = MFMA16(A3h[tn].v, rb.v, acc);
      acc = MFMA16(A3l[tn].v, rb.v, acc);
      gb[tn] = acc;
    }

    // ---- (3) L1 MFMAs (t+1): independent of gb; hides MFMA latency ----
    f32x4 gan[4];
#pragma unroll
    for (int tn = 0; tn < 4; ++tn) {
      f32x4 acc = MFMA16(A1h[tn].v, xch.v, bias1v[tn]);
      acc = MFMA16(A1l[tn].v, xch.v, acc);
      acc = MFMA16(A1h[tn].v, xcl.v, acc);
      acc = MFMA16(A2h[tn].v, hb.v, acc);
      acc = MFMA16(A2l[tn].v, hb.v, acc);
      gan[tn] = acc;
    }

    // ---- (4) convert x(t+2) from raw regs (loaded 2 iters ago) ----
    FragU nxh, nxl;
    cvt(rw, nxh, nxl);

    // ---- (5) issue raw load x(t+3); uniform guard past the end ----
    RawX rwn = loadraw((t <= 96) ? xq : x0);
    xq += adv;

    // ---- (6) L2 elementwise (t): gb arrived long ago ----
#pragma unroll
    for (int r = 0; r < 4; ++r) {
      const float iv = sigm(gb[0][r]);
      const float fv = sigm(gb[1][r]);
      const float gv = tanh_(gb[2][r]);
      const float ov = sigm(gb[3][r]);
      const float cc = fv * c2[r] + iv * gv;
      c2[r] = cc;
      const float h = ov * tanh_(cc);
      h2v[r] = h;
      h2b.d[r] = split_pack(h);
    }

    // rotate pipeline registers (elided by unroll-2 ping-pong)
#pragma unroll
    for (int tn = 0; tn < 4; ++tn) ga[tn] = gan[tn];
    xch = nxh;
    xcl = nxl;
    rw = rwn;
  }

  // ---- output: relu(h2_last); lane (b,g) holds units 4g..4g+3 of batch b ----
  f32x4 o;
#pragma unroll
  for (int r = 0; r < 4; ++r) o[r] = fmaxf(h2v[r], 0.f);
  *(f32x4*)(out + (size_t)(b0 + b) * 16 + 4 * g) = o;  // 16B-aligned

  (void)x0;
}

extern "C" void kernel_launch(void* const* d_in, const int* in_sizes, int n_in,
                              void* d_out, int out_size, void* d_ws, size_t ws_size,
                              hipStream_t stream) {
  (void)in_sizes; (void)n_in; (void)d_ws; (void)ws_size; (void)out_size;
  // 16384 batch / 16 per wave / 4 waves per block = 256 blocks (1 per CU).
  enc_kernel<<<dim3(256), dim3(256), 0, stream>>>(
      (const float*)d_in[0],
      (const float*)d_in[1],
      (const float*)d_in[2],
      (const float*)d_in[3],
      (const float*)d_in[4],
      (const float*)d_in[5],
      (const float*)d_in[6],
      (const float*)d_in[7],
      (const float*)d_in[8],
      (float*)d_out);
}